// Round 9
// baseline (234.003 us; speedup 1.0000x reference)
//
#include <hip/hip_runtime.h>

// GCN encoder: h = relu(agg(x)@W1 + b1); out = agg(h@W2) + b2
// agg = symmetric-normalized adjacency (self loops) aggregation.
// Identities: agg(x@W)==agg(x)@W; (dinv*h)@W==dinv*(h@W).
// All GEMM operands bf16 -> MFMA (f32 accumulate). Gather tables bf16.
// CSR build: count's atomicAdd return = edge rank; SLAB col (CAP=56/node)
// -> no prefix scan, no row_start, atomic-free fill. x->bf16 convert is
// UNSCALED and fused into the count kernel (independent streaming work
// hidden under the atomic-throughput-bound count, which idles at 10% BW);
// agg1 applies per-edge norm rsqrtf(counts[s]+1) from the L2-resident
// counts table instead (parallel 4B loads, VALU has headroom).

constexpr int N  = 100000;
constexpr int E  = 1600000;
constexpr int NB = (N + 255) / 256;
constexpr int CAP = 56;                    // slab capacity; P(Poisson(16)>56)~1e-11
constexpr int EB = (E + 255) / 256;        // 6250 edge blocks
constexpr int CB = (N * 16 + 255) / 256;   // 6250 convert blocks

typedef unsigned short u16;
typedef __attribute__((ext_vector_type(8))) short bf16x8;  // 8 bf16 = 4 VGPR
typedef __attribute__((ext_vector_type(4))) float f32x4;

// ---------------- bf16 helpers ----------------

__device__ __forceinline__ unsigned bf16rne(float f) {
  unsigned u = __float_as_uint(f);
  return (u + 0x7fffu + ((u >> 16) & 1u)) >> 16;
}
__device__ __forceinline__ unsigned pk(float lo, float hi) {
  return bf16rne(lo) | (bf16rne(hi) << 16);
}
__device__ __forceinline__ void acc8(float (&a)[8], const uint4& u, float wgt) {
  a[0] = fmaf(wgt, __uint_as_float(u.x << 16), a[0]);
  a[1] = fmaf(wgt, __uint_as_float(u.x & 0xffff0000u), a[1]);
  a[2] = fmaf(wgt, __uint_as_float(u.y << 16), a[2]);
  a[3] = fmaf(wgt, __uint_as_float(u.y & 0xffff0000u), a[3]);
  a[4] = fmaf(wgt, __uint_as_float(u.z << 16), a[4]);
  a[5] = fmaf(wgt, __uint_as_float(u.z & 0xffff0000u), a[5]);
  a[6] = fmaf(wgt, __uint_as_float(u.w << 16), a[6]);
  a[7] = fmaf(wgt, __uint_as_float(u.w & 0xffff0000u), a[7]);
}

// ---------------- fused: degree count (+rank) | x -> bf16 (unscaled) -------

__global__ __launch_bounds__(256) void k_count_conv(
    const int* __restrict__ dst, int* __restrict__ counts, int* __restrict__ rank,
    const float* __restrict__ x, uint4* __restrict__ xb) {
  int b = blockIdx.x;
  if (b < EB) {
    int e = b * 256 + threadIdx.x;
    if (e < E) rank[e] = atomicAdd(&counts[dst[e]], 1);
  } else {
    int i = (b - EB) * 256 + threadIdx.x;   // one uint4 (8 bf16) per thread
    if (i >= N * 16) return;
    const float4* x4 = reinterpret_cast<const float4*>(x);
    float4 v0 = x4[(size_t)i * 2];
    float4 v1 = x4[(size_t)i * 2 + 1];
    uint4 o;
    o.x = pk(v0.x, v0.y);
    o.y = pk(v0.z, v0.w);
    o.z = pk(v1.x, v1.y);
    o.w = pk(v1.z, v1.w);
    xb[i] = o;
  }
}

__global__ void k_finish(const int* __restrict__ counts, float* __restrict__ dinv) {
  int i = blockIdx.x * 256 + threadIdx.x;
  if (i < N) dinv[i] = rsqrtf((float)(counts[i] + 1));  // +1 self loop
}

// ---------------- atomic-free slab fill ----------------

__global__ __launch_bounds__(256) void k_fill(
    const int* __restrict__ src, const int* __restrict__ dst,
    const int* __restrict__ rank, int* __restrict__ col) {
  int e = blockIdx.x * 256 + threadIdx.x;
  if (e < E) col[(size_t)dst[e] * CAP + rank[e]] = src[e];
}

// ---------------- W -> bf16 in MFMA B-fragment order ----------------
// Fragment f = (ct*4+kc)*64 + lane holds B[kc*32 + (lane>>4)*8 + j][ct*16 + (lane&15)]

__global__ __launch_bounds__(256) void k_wprep(
    const float* __restrict__ W1, const float* __restrict__ W2,
    uint4* __restrict__ Wb1, uint4* __restrict__ Wb2) {
  int t = blockIdx.x * 256 + threadIdx.x;
  if (t < 2048) {                      // W1: 8 ct * 4 kc * 64 lanes
    int ct = t >> 8, kc = (t >> 6) & 3, l = t & 63;
    int k0 = kc * 32 + (l >> 4) * 8;
    int c = ct * 16 + (l & 15);
    uint4 o;
    o.x = pk(W1[(k0 + 0) * 128 + c], W1[(k0 + 1) * 128 + c]);
    o.y = pk(W1[(k0 + 2) * 128 + c], W1[(k0 + 3) * 128 + c]);
    o.z = pk(W1[(k0 + 4) * 128 + c], W1[(k0 + 5) * 128 + c]);
    o.w = pk(W1[(k0 + 6) * 128 + c], W1[(k0 + 7) * 128 + c]);
    Wb1[t] = o;
  } else if (t < 3072) {               // W2: 4 ct * 4 kc * 64 lanes
    int u = t - 2048;
    int ct = u >> 8, kc = (u >> 6) & 3, l = u & 63;
    int k0 = kc * 32 + (l >> 4) * 8;
    int c = ct * 16 + (l & 15);
    uint4 o;
    o.x = pk(W2[(k0 + 0) * 64 + c], W2[(k0 + 1) * 64 + c]);
    o.y = pk(W2[(k0 + 2) * 64 + c], W2[(k0 + 3) * 64 + c]);
    o.z = pk(W2[(k0 + 4) * 64 + c], W2[(k0 + 5) * 64 + c]);
    o.w = pk(W2[(k0 + 6) * 64 + c], W2[(k0 + 7) * 64 + c]);
    Wb2[u] = o;
  }
}

// ---------------- aggregation: bf16 gather, f32 accumulate ----------
// SRC_W=1 (layer 1, unscaled table): w_s = rsqrtf(counts[s]+1), self w = di.
// SRC_W=0 (layer 2, prescaled table): w_s = 1, self w = 1.
// out[i] = di * ( sum_s w_s * t[s] + w_self * t[i] ) [+ bias]

template <int DIM, bool SRC_W, bool BIAS, bool OUT_BF16>
__global__ __launch_bounds__(256) void k_agg(
    const uint4* __restrict__ t, const int* __restrict__ counts,
    const int* __restrict__ col, const float* __restrict__ dinv,
    const float* __restrict__ bias, void* __restrict__ out) {
  constexpr int L = DIM / 8;                 // 16 (DIM=128) or 8 (DIM=64)
  constexpr int NPB = 256 / L;
  const int node = blockIdx.x * NPB + threadIdx.x / L;
  const int lane = threadIdx.x % L;
  if (node >= N) return;
  const size_t s0 = (size_t)node * CAP;
  const int cnt = counts[node];
  const float di = dinv[node];

  float a[8] = {0, 0, 0, 0, 0, 0, 0, 0};
  acc8(a, t[(size_t)node * L + lane], SRC_W ? di : 1.0f);  // self loop
  for (int e = 0; e < cnt; e += 4) {
    const int last = cnt - 1;
    int sA = col[s0 + e];
    int sB = col[s0 + min(e + 1, last)];
    int sC = col[s0 + min(e + 2, last)];
    int sD = col[s0 + min(e + 3, last)];
    float wA, wB, wC, wD;
    if (SRC_W) {
      wA = rsqrtf((float)(counts[sA] + 1));
      wB = (e + 1 <= last) ? rsqrtf((float)(counts[sB] + 1)) : 0.0f;
      wC = (e + 2 <= last) ? rsqrtf((float)(counts[sC] + 1)) : 0.0f;
      wD = (e + 3 <= last) ? rsqrtf((float)(counts[sD] + 1)) : 0.0f;
    } else {
      wA = 1.0f;
      wB = (e + 1 <= last) ? 1.0f : 0.0f;
      wC = (e + 2 <= last) ? 1.0f : 0.0f;
      wD = (e + 3 <= last) ? 1.0f : 0.0f;
    }
    uint4 vA = t[(size_t)sA * L + lane];
    uint4 vB = t[(size_t)sB * L + lane];
    uint4 vC = t[(size_t)sC * L + lane];
    uint4 vD = t[(size_t)sD * L + lane];
    acc8(a, vA, wA);
    acc8(a, vB, wB);
    acc8(a, vC, wC);
    acc8(a, vD, wD);
  }
  if (OUT_BF16) {
    uint4 o;
    o.x = pk(di * a[0], di * a[1]);
    o.y = pk(di * a[2], di * a[3]);
    o.z = pk(di * a[4], di * a[5]);
    o.w = pk(di * a[6], di * a[7]);
    reinterpret_cast<uint4*>(out)[(size_t)node * L + lane] = o;
  } else {
    float4 r0 = {di * a[0], di * a[1], di * a[2], di * a[3]};
    float4 r1 = {di * a[4], di * a[5], di * a[6], di * a[7]};
    if (BIAS) {
      const float4* b4 = reinterpret_cast<const float4*>(bias) + lane * 2;
      float4 b0 = b4[0], b1 = b4[1];
      r0.x += b0.x; r0.y += b0.y; r0.z += b0.z; r0.w += b0.w;
      r1.x += b1.x; r1.y += b1.y; r1.z += b1.z; r1.w += b1.w;
    }
    float4* o4 = reinterpret_cast<float4*>(out) + (size_t)node * (DIM / 4) + lane * 2;
    o4[0] = r0;
    o4[1] = r1;
  }
}

// ---------------- MFMA GEMM: out[N,OUTC](bf16) = A[N,128](bf16) @ Wsw ------
// 4 waves/block; each wave owns a full 16-row x OUTC strip (grid-stride).
// B fragments in registers; no LDS, no barriers.
// EPI1: v = relu(v + bias[col]) * dinv[row]  (layer-1 epilogue -> hs)

template <int OUTC, bool EPI1>
__global__ __launch_bounds__(256, 1) void k_gemm_mfma(
    const u16* __restrict__ A, const uint4* __restrict__ Wsw,
    const float* __restrict__ bias, const float* __restrict__ dinv,
    u16* __restrict__ out) {
  constexpr int CT = OUTC / 16;
  const int lane = threadIdx.x & 63;
  const int lr = lane & 15;
  const int lk = lane >> 4;
  const int gw = blockIdx.x * 4 + (threadIdx.x >> 6);
  const int nw = gridDim.x * 4;
  const bf16x8* Wf = reinterpret_cast<const bf16x8*>(Wsw);

  bf16x8 b[CT][4];
  #pragma unroll
  for (int ct = 0; ct < CT; ++ct)
    #pragma unroll
    for (int kc = 0; kc < 4; ++kc)
      b[ct][kc] = Wf[(ct * 4 + kc) * 64 + lane];

  float bl[CT];
  if (EPI1) {
    #pragma unroll
    for (int ct = 0; ct < CT; ++ct) bl[ct] = bias[ct * 16 + lr];
  }

  const f32x4 fz = {0.f, 0.f, 0.f, 0.f};
  for (int s = gw; s < N / 16; s += nw) {
    const u16* ar = A + (size_t)(s * 16 + lr) * 128 + lk * 8;
    bf16x8 a[4];
    #pragma unroll
    for (int kc = 0; kc < 4; ++kc)
      a[kc] = *reinterpret_cast<const bf16x8*>(ar + kc * 32);
    f32x4 acc[CT];
    #pragma unroll
    for (int ct = 0; ct < CT; ++ct) acc[ct] = fz;
    #pragma unroll
    for (int kc = 0; kc < 4; ++kc)
      #pragma unroll
      for (int ct = 0; ct < CT; ++ct)
        acc[ct] = __builtin_amdgcn_mfma_f32_16x16x32_bf16(a[kc], b[ct][kc],
                                                          acc[ct], 0, 0, 0);
    const int rbase = s * 16 + lk * 4;
    float dv[4];
    if (EPI1) {
      #pragma unroll
      for (int ri = 0; ri < 4; ++ri) dv[ri] = dinv[rbase + ri];
    }
    #pragma unroll
    for (int ct = 0; ct < CT; ++ct) {
      const int c = ct * 16 + lr;
      #pragma unroll
      for (int ri = 0; ri < 4; ++ri) {
        float v = acc[ct][ri];
        if (EPI1) v = fmaxf(v + bl[ct], 0.f) * dv[ri];
        out[(size_t)(rbase + ri) * OUTC + c] = (u16)bf16rne(v);
      }
    }
  }
}

// ---------------- launch ----------------

extern "C" void kernel_launch(void* const* d_in, const int* in_sizes, int n_in,
                              void* d_out, int out_size, void* d_ws, size_t ws_size,
                              hipStream_t stream) {
  const float* x  = (const float*)d_in[0];
  const int*   ei = (const int*)d_in[1];
  const float* W1 = (const float*)d_in[2];
  const float* b1 = (const float*)d_in[3];
  const float* W2 = (const float*)d_in[4];
  const float* b2 = (const float*)d_in[5];
  float* out = (float*)d_out;
  const int* src = ei;
  const int* dst = ei + E;

  char* p = (char*)d_ws;
  auto alloc = [&](size_t bytes) {
    void* q = p;
    p += (bytes + 255) & ~size_t(255);
    return q;
  };
  int*   counts = (int*)alloc((size_t)N * 4);        // 0.4 MB
  int*   rank   = (int*)alloc((size_t)E * 4);        // 6.4 MB
  int*   col    = (int*)alloc((size_t)N * CAP * 4);  // 22.4 MB slab
  float* dinv   = (float*)alloc((size_t)N * 4);      // 0.4 MB
  uint4* xb     = (uint4*)alloc((size_t)N * 256);    // 25.6 MB: bf16 x, then hs
  uint4* xa     = (uint4*)alloc((size_t)N * 256);    // 25.6 MB: agg1 out, then L2 table
  uint4* Wb1    = (uint4*)alloc(2048 * 16);
  uint4* Wb2    = (uint4*)alloc(1024 * 16);

  (void)hipMemsetAsync(counts, 0, (size_t)N * 4, stream);
  k_wprep<<<12, 256, 0, stream>>>(W1, W2, Wb1, Wb2);
  k_count_conv<<<EB + CB, 256, 0, stream>>>(dst, counts, rank, x, xb);
  k_finish<<<NB, 256, 0, stream>>>(counts, dinv);
  k_fill<<<EB, 256, 0, stream>>>(src, dst, rank, col);

  // layer 1: gather-agg (unscaled bf16 table, per-edge norm) -> MFMA GEMM -> hs bf16
  k_agg<128, true, false, true><<<(N + 15) / 16, 256, 0, stream>>>(
      xb, counts, col, dinv, nullptr, xa);
  k_gemm_mfma<128, true><<<512, 256, 0, stream>>>(
      (const u16*)xa, Wb1, b1, dinv, (u16*)xb);

  // layer 2: MFMA GEMM -> bf16 table (prescaled rows) -> gather-agg + bias -> out
  k_gemm_mfma<64, false><<<512, 256, 0, stream>>>(
      (const u16*)xb, Wb2, nullptr, nullptr, (u16*)xa);
  k_agg<64, false, true, false><<<(N + 31) / 32, 256, 0, stream>>>(
      xa, counts, col, dinv, b2, out);
}

// Round 11
// 208.708 us; speedup vs baseline: 1.1212x; 1.1212x over previous
//
#include <hip/hip_runtime.h>

// GCN encoder: h = relu(agg(x)@W1 + b1); out = agg(h@W2) + b2
// agg = symmetric-normalized adjacency (self loops) aggregation.
// Identities: agg(x@W)==agg(x)@W; (dinv*h)@W==dinv*(h@W); di*(acc@W)==(di*acc)@W.
// Pipeline (6 dispatches):
//   memset counts; wprep (W->bf16 MFMA-frag tables);
//   count_conv:  per-edge atomicAdd rank (throughput floor ~24G/s) || x->bf16 xb
//   fill:        atomic-free slab scatter col[dst*CAP+rank]=src
//   k_layer1:    MEGA-FUSED per 16-node block: gather-agg (per-edge
//                w=rsqrt(counts[s]+1)) -> LDS -> MFMA @W1 (+bias,relu,*di,*di)
//                -> LDS -> MFMA @W2 -> bf16 layer-2 table. No xa/hs HBM
//                round-trips (saves ~102MB traffic + 2 launches).
//   agg2:        pure gather-sum over prescaled table, *di + b2 -> f32 out.

constexpr int N  = 100000;
constexpr int E  = 1600000;
constexpr int CAP = 56;                    // slab capacity; P(Poisson(16)>56)~1e-11
constexpr int EB = (E + 255) / 256;        // 6250 edge blocks
constexpr int CB = (N * 16 + 255) / 256;   // 6250 convert blocks

typedef unsigned short u16;
typedef __attribute__((ext_vector_type(8))) short bf16x8;  // 8 bf16 = 4 VGPR
typedef __attribute__((ext_vector_type(4))) float f32x4;

// ---------------- bf16 helpers ----------------

__device__ __forceinline__ unsigned bf16rne(float f) {
  unsigned u = __float_as_uint(f);
  return (u + 0x7fffu + ((u >> 16) & 1u)) >> 16;
}
__device__ __forceinline__ unsigned pk(float lo, float hi) {
  return bf16rne(lo) | (bf16rne(hi) << 16);
}
__device__ __forceinline__ void acc8(float (&a)[8], const uint4& u, float wgt) {
  a[0] = fmaf(wgt, __uint_as_float(u.x << 16), a[0]);
  a[1] = fmaf(wgt, __uint_as_float(u.x & 0xffff0000u), a[1]);
  a[2] = fmaf(wgt, __uint_as_float(u.y << 16), a[2]);
  a[3] = fmaf(wgt, __uint_as_float(u.y & 0xffff0000u), a[3]);
  a[4] = fmaf(wgt, __uint_as_float(u.z << 16), a[4]);
  a[5] = fmaf(wgt, __uint_as_float(u.z & 0xffff0000u), a[5]);
  a[6] = fmaf(wgt, __uint_as_float(u.w << 16), a[6]);
  a[7] = fmaf(wgt, __uint_as_float(u.w & 0xffff0000u), a[7]);
}

// ---------------- fused: degree count (+rank) | x -> bf16 (unscaled) -------

__global__ __launch_bounds__(256) void k_count_conv(
    const int* __restrict__ dst, int* __restrict__ counts, int* __restrict__ rank,
    const float* __restrict__ x, uint4* __restrict__ xb) {
  int b = blockIdx.x;
  if (b < EB) {
    int e = b * 256 + threadIdx.x;
    if (e < E) rank[e] = atomicAdd(&counts[dst[e]], 1);
  } else {
    int i = (b - EB) * 256 + threadIdx.x;   // one uint4 (8 bf16) per thread
    if (i >= N * 16) return;
    const float4* x4 = reinterpret_cast<const float4*>(x);
    float4 v0 = x4[(size_t)i * 2];
    float4 v1 = x4[(size_t)i * 2 + 1];
    uint4 o;
    o.x = pk(v0.x, v0.y);
    o.y = pk(v0.z, v0.w);
    o.z = pk(v1.x, v1.y);
    o.w = pk(v1.z, v1.w);
    xb[i] = o;
  }
}

// ---------------- atomic-free slab fill ----------------

__global__ __launch_bounds__(256) void k_fill(
    const int* __restrict__ src, const int* __restrict__ dst,
    const int* __restrict__ rank, int* __restrict__ col) {
  int e = blockIdx.x * 256 + threadIdx.x;
  if (e < E) col[(size_t)dst[e] * CAP + rank[e]] = src[e];
}

// ---------------- W -> bf16 in MFMA B-fragment order ----------------
// Fragment f = (ct*4+kc)*64 + lane holds B[kc*32 + (lane>>4)*8 + j][ct*16 + (lane&15)]

__global__ __launch_bounds__(256) void k_wprep(
    const float* __restrict__ W1, const float* __restrict__ W2,
    uint4* __restrict__ Wb1, uint4* __restrict__ Wb2) {
  int t = blockIdx.x * 256 + threadIdx.x;
  if (t < 2048) {                      // W1: 8 ct * 4 kc * 64 lanes
    int ct = t >> 8, kc = (t >> 6) & 3, l = t & 63;
    int k0 = kc * 32 + (l >> 4) * 8;
    int c = ct * 16 + (l & 15);
    uint4 o;
    o.x = pk(W1[(k0 + 0) * 128 + c], W1[(k0 + 1) * 128 + c]);
    o.y = pk(W1[(k0 + 2) * 128 + c], W1[(k0 + 3) * 128 + c]);
    o.z = pk(W1[(k0 + 4) * 128 + c], W1[(k0 + 5) * 128 + c]);
    o.w = pk(W1[(k0 + 6) * 128 + c], W1[(k0 + 7) * 128 + c]);
    Wb1[t] = o;
  } else if (t < 3072) {               // W2: 4 ct * 4 kc * 64 lanes
    int u = t - 2048;
    int ct = u >> 8, kc = (u >> 6) & 3, l = u & 63;
    int k0 = kc * 32 + (l >> 4) * 8;
    int c = ct * 16 + (l & 15);
    uint4 o;
    o.x = pk(W2[(k0 + 0) * 64 + c], W2[(k0 + 1) * 64 + c]);
    o.y = pk(W2[(k0 + 2) * 64 + c], W2[(k0 + 3) * 64 + c]);
    o.z = pk(W2[(k0 + 4) * 64 + c], W2[(k0 + 5) * 64 + c]);
    o.w = pk(W2[(k0 + 6) * 64 + c], W2[(k0 + 7) * 64 + c]);
    Wb2[u] = o;
  }
}

// ---------------- MEGA layer 1: agg -> @W1 -> epi -> @W2 -> table ----------
// One block = 16 nodes, 256 threads.
// Phase A: thread (n=tid>>4, d8=tid&15) aggregates 8 dims of node n:
//   acc = sum_{s in in(n)} rsqrt(cnt_s+1)*xb[s] + rsqrt(cnt_n+1)*xb[n]
//   -> bf16 -> lds_a[n][d8*8..]  (row stride 136 u16 = 272B, 2-way banks max)
// Phase B: wave w computes cols [w*32,w*32+32) of acc@W1 (rows = block's 16):
//   v = relu(di[r]*v + b1[c]) * di[r]  -> lds_h (bf16)
// Phase C: wave w computes cols [w*16,w*16+16) of hs@W2 -> xa2 global (bf16).

__global__ __launch_bounds__(256) void k_layer1(
    const uint4* __restrict__ xb, const int* __restrict__ counts,
    const int* __restrict__ col, const float* __restrict__ b1,
    const uint4* __restrict__ Wb1, const uint4* __restrict__ Wb2,
    u16* __restrict__ xa2) {
  __shared__ u16 lds_a[16][136];
  __shared__ u16 lds_h[16][136];
  __shared__ float lds_di[16];
  const int tid = threadIdx.x;
  const int nodeBase = blockIdx.x * 16;

  // ---- phase A: gather-aggregate ----
  {
    const int n = tid >> 4;
    const int d8 = tid & 15;
    const int node = nodeBase + n;
    const int cnt = counts[node];
    const float wself = rsqrtf((float)(cnt + 1));
    if (d8 == 0) lds_di[n] = wself;
    const size_t s0 = (size_t)node * CAP;

    float a[8] = {0, 0, 0, 0, 0, 0, 0, 0};
    acc8(a, xb[(size_t)node * 16 + d8], wself);  // self loop
    int e = 0;
    for (; e + 4 <= cnt; e += 4) {               // full quads, no clamping
      int sA = col[s0 + e];
      int sB = col[s0 + e + 1];
      int sC = col[s0 + e + 2];
      int sD = col[s0 + e + 3];
      float wA = rsqrtf((float)(counts[sA] + 1));
      float wB = rsqrtf((float)(counts[sB] + 1));
      float wC = rsqrtf((float)(counts[sC] + 1));
      float wD = rsqrtf((float)(counts[sD] + 1));
      uint4 vA = xb[(size_t)sA * 16 + d8];
      uint4 vB = xb[(size_t)sB * 16 + d8];
      uint4 vC = xb[(size_t)sC * 16 + d8];
      uint4 vD = xb[(size_t)sD * 16 + d8];
      acc8(a, vA, wA);
      acc8(a, vB, wB);
      acc8(a, vC, wC);
      acc8(a, vD, wD);
    }
    for (; e < cnt; ++e) {                       // exact tail
      int s = col[s0 + e];
      float w = rsqrtf((float)(counts[s] + 1));
      acc8(a, xb[(size_t)s * 16 + d8], w);
    }
    uint4 o;
    o.x = pk(a[0], a[1]);
    o.y = pk(a[2], a[3]);
    o.z = pk(a[4], a[5]);
    o.w = pk(a[6], a[7]);
    *reinterpret_cast<uint4*>(&lds_a[n][d8 * 8]) = o;
  }
  __syncthreads();

  // ---- phase B: acc@W1, epilogue relu(di*v+b1)*di -> lds_h ----
  const int lane = tid & 63;
  const int w = tid >> 6;
  const int lr = lane & 15;
  const int lk = lane >> 4;
  const bf16x8* Wf1 = reinterpret_cast<const bf16x8*>(Wb1);
  const bf16x8* Wf2 = reinterpret_cast<const bf16x8*>(Wb2);
  const f32x4 fz = {0.f, 0.f, 0.f, 0.f};
  {
    bf16x8 af[4];
    #pragma unroll
    for (int kc = 0; kc < 4; ++kc)
      af[kc] = *reinterpret_cast<const bf16x8*>(&lds_a[lr][kc * 32 + lk * 8]);
    f32x4 acc1[2] = {fz, fz};
    #pragma unroll
    for (int kc = 0; kc < 4; ++kc) {
      #pragma unroll
      for (int i = 0; i < 2; ++i) {
        bf16x8 bf = Wf1[((w * 2 + i) * 4 + kc) * 64 + lane];
        acc1[i] = __builtin_amdgcn_mfma_f32_16x16x32_bf16(af[kc], bf, acc1[i], 0, 0, 0);
      }
    }
    #pragma unroll
    for (int i = 0; i < 2; ++i) {
      const int c = (w * 2 + i) * 16 + lr;
      const float bl = b1[c];
      #pragma unroll
      for (int ri = 0; ri < 4; ++ri) {
        const int r = lk * 4 + ri;
        const float di = lds_di[r];
        float v = fmaxf(di * acc1[i][ri] + bl, 0.f) * di;
        lds_h[r][c] = (u16)bf16rne(v);
      }
    }
  }
  __syncthreads();

  // ---- phase C: hs@W2 -> layer-2 table (bf16) ----
  {
    bf16x8 a2[4];
    #pragma unroll
    for (int kc = 0; kc < 4; ++kc)
      a2[kc] = *reinterpret_cast<const bf16x8*>(&lds_h[lr][kc * 32 + lk * 8]);
    f32x4 acc2 = fz;
    #pragma unroll
    for (int kc = 0; kc < 4; ++kc) {
      bf16x8 bf = Wf2[(w * 4 + kc) * 64 + lane];
      acc2 = __builtin_amdgcn_mfma_f32_16x16x32_bf16(a2[kc], bf, acc2, 0, 0, 0);
    }
    #pragma unroll
    for (int ri = 0; ri < 4; ++ri) {
      const int row = nodeBase + lk * 4 + ri;
      xa2[(size_t)row * 64 + w * 16 + lr] = (u16)bf16rne(acc2[ri]);
    }
  }
}

// ---------------- layer-2 aggregation: prescaled bf16 table ----------------
// out[i] = rsqrt(cnt_i+1) * ( sum_s t[s] + t[i] ) + b2    (f32 out)

__global__ __launch_bounds__(256) void k_agg2(
    const uint4* __restrict__ t, const int* __restrict__ counts,
    const int* __restrict__ col, const float* __restrict__ bias,
    float* __restrict__ out) {
  const int node = blockIdx.x * 32 + (threadIdx.x >> 3);
  const int lane = threadIdx.x & 7;            // 8 lanes x 8 dims = 64
  if (node >= N) return;
  const size_t s0 = (size_t)node * CAP;
  const int cnt = counts[node];
  const float di = rsqrtf((float)(cnt + 1));

  float a[8] = {0, 0, 0, 0, 0, 0, 0, 0};
  acc8(a, t[(size_t)node * 8 + lane], 1.0f);   // self loop (prescaled)
  int e = 0;
  for (; e + 4 <= cnt; e += 4) {
    int sA = col[s0 + e];
    int sB = col[s0 + e + 1];
    int sC = col[s0 + e + 2];
    int sD = col[s0 + e + 3];
    uint4 vA = t[(size_t)sA * 8 + lane];
    uint4 vB = t[(size_t)sB * 8 + lane];
    uint4 vC = t[(size_t)sC * 8 + lane];
    uint4 vD = t[(size_t)sD * 8 + lane];
    acc8(a, vA, 1.0f);
    acc8(a, vB, 1.0f);
    acc8(a, vC, 1.0f);
    acc8(a, vD, 1.0f);
  }
  for (; e < cnt; ++e)
    acc8(a, t[(size_t)col[s0 + e] * 8 + lane], 1.0f);

  const float4* b4 = reinterpret_cast<const float4*>(bias) + lane * 2;
  float4 b0 = b4[0], b1v = b4[1];
  float4 r0 = {fmaf(di, a[0], b0.x), fmaf(di, a[1], b0.y),
               fmaf(di, a[2], b0.z), fmaf(di, a[3], b0.w)};
  float4 r1 = {fmaf(di, a[4], b1v.x), fmaf(di, a[5], b1v.y),
               fmaf(di, a[6], b1v.z), fmaf(di, a[7], b1v.w)};
  float4* o4 = reinterpret_cast<float4*>(out) + (size_t)node * 16 + lane * 2;
  o4[0] = r0;
  o4[1] = r1;
}

// ---------------- launch ----------------

extern "C" void kernel_launch(void* const* d_in, const int* in_sizes, int n_in,
                              void* d_out, int out_size, void* d_ws, size_t ws_size,
                              hipStream_t stream) {
  const float* x  = (const float*)d_in[0];
  const int*   ei = (const int*)d_in[1];
  const float* W1 = (const float*)d_in[2];
  const float* b1 = (const float*)d_in[3];
  const float* W2 = (const float*)d_in[4];
  const float* b2 = (const float*)d_in[5];
  float* out = (float*)d_out;
  const int* src = ei;
  const int* dst = ei + E;

  char* p = (char*)d_ws;
  auto alloc = [&](size_t bytes) {
    void* q = p;
    p += (bytes + 255) & ~size_t(255);
    return q;
  };
  int*   counts = (int*)alloc((size_t)N * 4);        // 0.4 MB
  int*   rank   = (int*)alloc((size_t)E * 4);        // 6.4 MB
  int*   col    = (int*)alloc((size_t)N * CAP * 4);  // 22.4 MB slab
  uint4* xb     = (uint4*)alloc((size_t)N * 256);    // 25.6 MB bf16 x (unscaled)
  u16*   xa2    = (u16*)alloc((size_t)N * 64 * 2);   // 12.8 MB layer-2 table
  uint4* Wb1    = (uint4*)alloc(2048 * 16);
  uint4* Wb2    = (uint4*)alloc(1024 * 16);

  (void)hipMemsetAsync(counts, 0, (size_t)N * 4, stream);
  k_wprep<<<12, 256, 0, stream>>>(W1, W2, Wb1, Wb2);
  k_count_conv<<<EB + CB, 256, 0, stream>>>(dst, counts, rank, x, xb);
  k_fill<<<EB, 256, 0, stream>>>(src, dst, rank, col);

  // layer 1 fused: gather-agg -> @W1 (+bias,relu,*di,*di) -> @W2 -> bf16 table
  k_layer1<<<N / 16, 256, 0, stream>>>(xb, counts, col, b1, Wb1, Wb2, xa2);

  // layer 2: gather-agg over prescaled table, *di + b2 -> f32 out
  k_agg2<<<N / 32, 256, 0, stream>>>(
      reinterpret_cast<const uint4*>(xa2), counts, col, b2, out);
}

// Round 12
// 201.161 us; speedup vs baseline: 1.1633x; 1.0375x over previous
//
#include <hip/hip_runtime.h>

// GCN encoder: h = relu(agg(x)@W1 + b1); out = agg(h@W2) + b2
// agg = symmetric-normalized adjacency (self loops) aggregation.
// Identities: agg(x@W)==agg(x)@W; (dinv*h)@W==dinv*(h@W); di*(acc@W)==(di*acc)@W.
// Pipeline (5 dispatches):
//   memset counts;
//   count_conv:  INTERLEAVED blocks: even=per-edge atomicAdd rank (atomic
//                floor ~24G ops/s, BW-idle), odd=x->bf16 convert (BW-bound),
//                trailing 12 = W->bf16 MFMA-frag prep. Convert+wprep hide
//                under the atomic pass instead of tailing it.
//   fill:        atomic-free slab scatter col[dst*CAP+rank]=src (write-
//                allocate floor ~102MB)
//   k_layer1:    per 16-node block: gather-agg (w=rsqrt(counts[s]+1), 410MB
//                L3 gather @ ~5.9TB/s) -> LDS -> MFMA @W1 (+bias,relu,*di,*di)
//                -> LDS -> MFMA @W2 -> bf16 layer-2 table
//   agg2:        gather-sum over prescaled table (205MB), *di + b2 -> f32 out

constexpr int N  = 100000;
constexpr int E  = 1600000;
constexpr int CAP = 56;                    // slab capacity; P(Poisson(16)>56)~1e-11
constexpr int EB = (E + 255) / 256;        // 6250 edge blocks
constexpr int CB = (N * 16 + 255) / 256;   // 6250 convert blocks (== EB)

typedef unsigned short u16;
typedef __attribute__((ext_vector_type(8))) short bf16x8;  // 8 bf16 = 4 VGPR
typedef __attribute__((ext_vector_type(4))) float f32x4;

// ---------------- bf16 helpers ----------------

__device__ __forceinline__ unsigned bf16rne(float f) {
  unsigned u = __float_as_uint(f);
  return (u + 0x7fffu + ((u >> 16) & 1u)) >> 16;
}
__device__ __forceinline__ unsigned pk(float lo, float hi) {
  return bf16rne(lo) | (bf16rne(hi) << 16);
}
__device__ __forceinline__ void acc8(float (&a)[8], const uint4& u, float wgt) {
  a[0] = fmaf(wgt, __uint_as_float(u.x << 16), a[0]);
  a[1] = fmaf(wgt, __uint_as_float(u.x & 0xffff0000u), a[1]);
  a[2] = fmaf(wgt, __uint_as_float(u.y << 16), a[2]);
  a[3] = fmaf(wgt, __uint_as_float(u.y & 0xffff0000u), a[3]);
  a[4] = fmaf(wgt, __uint_as_float(u.z << 16), a[4]);
  a[5] = fmaf(wgt, __uint_as_float(u.z & 0xffff0000u), a[5]);
  a[6] = fmaf(wgt, __uint_as_float(u.w << 16), a[6]);
  a[7] = fmaf(wgt, __uint_as_float(u.w & 0xffff0000u), a[7]);
}

// ------- fused: degree count (+rank) | x -> bf16 | W -> frag tables --------
// blocks [0,2*EB): even -> edge chunk (b>>1), odd -> convert chunk (b>>1).
// blocks [2*EB, 2*EB+12): weight prep (3072 threads of work).

__global__ __launch_bounds__(256) void k_count_conv(
    const int* __restrict__ dst, int* __restrict__ counts, int* __restrict__ rank,
    const float* __restrict__ x, uint4* __restrict__ xb,
    const float* __restrict__ W1, const float* __restrict__ W2,
    uint4* __restrict__ Wb1, uint4* __restrict__ Wb2) {
  int b = blockIdx.x;
  if (b < 2 * EB) {
    int c = b >> 1;
    if (b & 1) {                             // convert block
      int i = c * 256 + threadIdx.x;         // one uint4 (8 bf16) per thread
      if (i >= N * 16) return;
      const float4* x4 = reinterpret_cast<const float4*>(x);
      float4 v0 = x4[(size_t)i * 2];
      float4 v1 = x4[(size_t)i * 2 + 1];
      uint4 o;
      o.x = pk(v0.x, v0.y);
      o.y = pk(v0.z, v0.w);
      o.z = pk(v1.x, v1.y);
      o.w = pk(v1.z, v1.w);
      xb[i] = o;
    } else {                                 // edge (count) block
      int e = c * 256 + threadIdx.x;
      if (e < E) rank[e] = atomicAdd(&counts[dst[e]], 1);
    }
  } else {                                   // weight prep
    int t = (b - 2 * EB) * 256 + threadIdx.x;
    if (t < 2048) {                          // W1: 8 ct * 4 kc * 64 lanes
      int ct = t >> 8, kc = (t >> 6) & 3, l = t & 63;
      int k0 = kc * 32 + (l >> 4) * 8;
      int c = ct * 16 + (l & 15);
      uint4 o;
      o.x = pk(W1[(k0 + 0) * 128 + c], W1[(k0 + 1) * 128 + c]);
      o.y = pk(W1[(k0 + 2) * 128 + c], W1[(k0 + 3) * 128 + c]);
      o.z = pk(W1[(k0 + 4) * 128 + c], W1[(k0 + 5) * 128 + c]);
      o.w = pk(W1[(k0 + 6) * 128 + c], W1[(k0 + 7) * 128 + c]);
      Wb1[t] = o;
    } else if (t < 3072) {                   // W2: 4 ct * 4 kc * 64 lanes
      int u = t - 2048;
      int ct = u >> 8, kc = (u >> 6) & 3, l = u & 63;
      int k0 = kc * 32 + (l >> 4) * 8;
      int c = ct * 16 + (l & 15);
      uint4 o;
      o.x = pk(W2[(k0 + 0) * 64 + c], W2[(k0 + 1) * 64 + c]);
      o.y = pk(W2[(k0 + 2) * 64 + c], W2[(k0 + 3) * 64 + c]);
      o.z = pk(W2[(k0 + 4) * 64 + c], W2[(k0 + 5) * 64 + c]);
      o.w = pk(W2[(k0 + 6) * 64 + c], W2[(k0 + 7) * 64 + c]);
      Wb2[u] = o;
    }
  }
}

// ---------------- atomic-free slab fill ----------------

__global__ __launch_bounds__(256) void k_fill(
    const int* __restrict__ src, const int* __restrict__ dst,
    const int* __restrict__ rank, int* __restrict__ col) {
  int e = blockIdx.x * 256 + threadIdx.x;
  if (e < E) col[(size_t)dst[e] * CAP + rank[e]] = src[e];
}

// ---------------- MEGA layer 1: agg -> @W1 -> epi -> @W2 -> table ----------
// One block = 16 nodes, 256 threads.
// Phase A: thread (n=tid>>4, d8=tid&15) aggregates 8 dims of node n:
//   acc = sum_{s in in(n)} rsqrt(cnt_s+1)*xb[s] + rsqrt(cnt_n+1)*xb[n]
//   -> bf16 -> lds_a[n][d8*8..]  (row stride 136 u16 = 272B, 2-way banks max)
// Phase B: wave w computes cols [w*32,w*32+32) of acc@W1 (rows = block's 16):
//   v = relu(di[r]*v + b1[c]) * di[r]  -> lds_h (bf16)
// Phase C: wave w computes cols [w*16,w*16+16) of hs@W2 -> xa2 global (bf16).

__global__ __launch_bounds__(256) void k_layer1(
    const uint4* __restrict__ xb, const int* __restrict__ counts,
    const int* __restrict__ col, const float* __restrict__ b1,
    const uint4* __restrict__ Wb1, const uint4* __restrict__ Wb2,
    u16* __restrict__ xa2) {
  __shared__ u16 lds_a[16][136];
  __shared__ u16 lds_h[16][136];
  __shared__ float lds_di[16];
  const int tid = threadIdx.x;
  const int nodeBase = blockIdx.x * 16;

  // ---- phase A: gather-aggregate ----
  {
    const int n = tid >> 4;
    const int d8 = tid & 15;
    const int node = nodeBase + n;
    const int cnt = counts[node];
    const float wself = rsqrtf((float)(cnt + 1));
    if (d8 == 0) lds_di[n] = wself;
    const size_t s0 = (size_t)node * CAP;

    float a[8] = {0, 0, 0, 0, 0, 0, 0, 0};
    acc8(a, xb[(size_t)node * 16 + d8], wself);  // self loop
    int e = 0;
    for (; e + 4 <= cnt; e += 4) {               // full quads, no clamping
      int sA = col[s0 + e];
      int sB = col[s0 + e + 1];
      int sC = col[s0 + e + 2];
      int sD = col[s0 + e + 3];
      float wA = rsqrtf((float)(counts[sA] + 1));
      float wB = rsqrtf((float)(counts[sB] + 1));
      float wC = rsqrtf((float)(counts[sC] + 1));
      float wD = rsqrtf((float)(counts[sD] + 1));
      uint4 vA = xb[(size_t)sA * 16 + d8];
      uint4 vB = xb[(size_t)sB * 16 + d8];
      uint4 vC = xb[(size_t)sC * 16 + d8];
      uint4 vD = xb[(size_t)sD * 16 + d8];
      acc8(a, vA, wA);
      acc8(a, vB, wB);
      acc8(a, vC, wC);
      acc8(a, vD, wD);
    }
    for (; e < cnt; ++e) {                       // exact tail
      int s = col[s0 + e];
      float w = rsqrtf((float)(counts[s] + 1));
      acc8(a, xb[(size_t)s * 16 + d8], w);
    }
    uint4 o;
    o.x = pk(a[0], a[1]);
    o.y = pk(a[2], a[3]);
    o.z = pk(a[4], a[5]);
    o.w = pk(a[6], a[7]);
    *reinterpret_cast<uint4*>(&lds_a[n][d8 * 8]) = o;
  }
  __syncthreads();

  // ---- phase B: acc@W1, epilogue relu(di*v+b1)*di -> lds_h ----
  const int lane = tid & 63;
  const int w = tid >> 6;
  const int lr = lane & 15;
  const int lk = lane >> 4;
  const bf16x8* Wf1 = reinterpret_cast<const bf16x8*>(Wb1);
  const bf16x8* Wf2 = reinterpret_cast<const bf16x8*>(Wb2);
  const f32x4 fz = {0.f, 0.f, 0.f, 0.f};
  {
    bf16x8 af[4];
    #pragma unroll
    for (int kc = 0; kc < 4; ++kc)
      af[kc] = *reinterpret_cast<const bf16x8*>(&lds_a[lr][kc * 32 + lk * 8]);
    f32x4 acc1[2] = {fz, fz};
    #pragma unroll
    for (int kc = 0; kc < 4; ++kc) {
      #pragma unroll
      for (int i = 0; i < 2; ++i) {
        bf16x8 bf = Wf1[((w * 2 + i) * 4 + kc) * 64 + lane];
        acc1[i] = __builtin_amdgcn_mfma_f32_16x16x32_bf16(af[kc], bf, acc1[i], 0, 0, 0);
      }
    }
    #pragma unroll
    for (int i = 0; i < 2; ++i) {
      const int c = (w * 2 + i) * 16 + lr;
      const float bl = b1[c];
      #pragma unroll
      for (int ri = 0; ri < 4; ++ri) {
        const int r = lk * 4 + ri;
        const float di = lds_di[r];
        float v = fmaxf(di * acc1[i][ri] + bl, 0.f) * di;
        lds_h[r][c] = (u16)bf16rne(v);
      }
    }
  }
  __syncthreads();

  // ---- phase C: hs@W2 -> layer-2 table (bf16) ----
  {
    bf16x8 a2[4];
    #pragma unroll
    for (int kc = 0; kc < 4; ++kc)
      a2[kc] = *reinterpret_cast<const bf16x8*>(&lds_h[lr][kc * 32 + lk * 8]);
    f32x4 acc2 = fz;
    #pragma unroll
    for (int kc = 0; kc < 4; ++kc) {
      bf16x8 bf = Wf2[(w * 4 + kc) * 64 + lane];
      acc2 = __builtin_amdgcn_mfma_f32_16x16x32_bf16(a2[kc], bf, acc2, 0, 0, 0);
    }
    #pragma unroll
    for (int ri = 0; ri < 4; ++ri) {
      const int row = nodeBase + lk * 4 + ri;
      xa2[(size_t)row * 64 + w * 16 + lr] = (u16)bf16rne(acc2[ri]);
    }
  }
}

// ---------------- layer-2 aggregation: prescaled bf16 table ----------------
// out[i] = rsqrt(cnt_i+1) * ( sum_s t[s] + t[i] ) + b2    (f32 out)

__global__ __launch_bounds__(256) void k_agg2(
    const uint4* __restrict__ t, const int* __restrict__ counts,
    const int* __restrict__ col, const float* __restrict__ bias,
    float* __restrict__ out) {
  const int node = blockIdx.x * 32 + (threadIdx.x >> 3);
  const int lane = threadIdx.x & 7;            // 8 lanes x 8 dims = 64
  if (node >= N) return;
  const size_t s0 = (size_t)node * CAP;
  const int cnt = counts[node];
  const float di = rsqrtf((float)(cnt + 1));

  float a[8] = {0, 0, 0, 0, 0, 0, 0, 0};
  acc8(a, t[(size_t)node * 8 + lane], 1.0f);   // self loop (prescaled)
  int e = 0;
  for (; e + 4 <= cnt; e += 4) {
    int sA = col[s0 + e];
    int sB = col[s0 + e + 1];
    int sC = col[s0 + e + 2];
    int sD = col[s0 + e + 3];
    uint4 vA = t[(size_t)sA * 8 + lane];
    uint4 vB = t[(size_t)sB * 8 + lane];
    uint4 vC = t[(size_t)sC * 8 + lane];
    uint4 vD = t[(size_t)sD * 8 + lane];
    acc8(a, vA, 1.0f);
    acc8(a, vB, 1.0f);
    acc8(a, vC, 1.0f);
    acc8(a, vD, 1.0f);
  }
  for (; e < cnt; ++e)
    acc8(a, t[(size_t)col[s0 + e] * 8 + lane], 1.0f);

  const float4* b4 = reinterpret_cast<const float4*>(bias) + lane * 2;
  float4 b0 = b4[0], b1v = b4[1];
  float4 r0 = {fmaf(di, a[0], b0.x), fmaf(di, a[1], b0.y),
               fmaf(di, a[2], b0.z), fmaf(di, a[3], b0.w)};
  float4 r1 = {fmaf(di, a[4], b1v.x), fmaf(di, a[5], b1v.y),
               fmaf(di, a[6], b1v.z), fmaf(di, a[7], b1v.w)};
  float4* o4 = reinterpret_cast<float4*>(out) + (size_t)node * 16 + lane * 2;
  o4[0] = r0;
  o4[1] = r1;
}

// ---------------- launch ----------------

extern "C" void kernel_launch(void* const* d_in, const int* in_sizes, int n_in,
                              void* d_out, int out_size, void* d_ws, size_t ws_size,
                              hipStream_t stream) {
  const float* x  = (const float*)d_in[0];
  const int*   ei = (const int*)d_in[1];
  const float* W1 = (const float*)d_in[2];
  const float* b1 = (const float*)d_in[3];
  const float* W2 = (const float*)d_in[4];
  const float* b2 = (const float*)d_in[5];
  float* out = (float*)d_out;
  const int* src = ei;
  const int* dst = ei + E;

  char* p = (char*)d_ws;
  auto alloc = [&](size_t bytes) {
    void* q = p;
    p += (bytes + 255) & ~size_t(255);
    return q;
  };
  int*   counts = (int*)alloc((size_t)N * 4);        // 0.4 MB
  int*   rank   = (int*)alloc((size_t)E * 4);        // 6.4 MB
  int*   col    = (int*)alloc((size_t)N * CAP * 4);  // 22.4 MB slab
  uint4* xb     = (uint4*)alloc((size_t)N * 256);    // 25.6 MB bf16 x (unscaled)
  u16*   xa2    = (u16*)alloc((size_t)N * 64 * 2);   // 12.8 MB layer-2 table
  uint4* Wb1    = (uint4*)alloc(2048 * 16);
  uint4* Wb2    = (uint4*)alloc(1024 * 16);

  (void)hipMemsetAsync(counts, 0, (size_t)N * 4, stream);
  k_count_conv<<<2 * EB + 12, 256, 0, stream>>>(dst, counts, rank, x, xb,
                                                W1, W2, Wb1, Wb2);
  k_fill<<<EB, 256, 0, stream>>>(src, dst, rank, col);

  // layer 1 fused: gather-agg -> @W1 (+bias,relu,*di,*di) -> @W2 -> bf16 table
  k_layer1<<<N / 16, 256, 0, stream>>>(xb, counts, col, b1, Wb1, Wb2, xa2);

  // layer 2: gather-agg over prescaled table, *di + b2 -> f32 out
  k_agg2<<<N / 32, 256, 0, stream>>>(
      reinterpret_cast<const uint4*>(xa2), counts, col, b2, out);
}